// Round 1
// baseline (544.366 us; speedup 1.0000x reference)
//
#include <hip/hip_runtime.h>
#include <math.h>

// NM-LSTM step, B=256, IN=HS=512, NM=1, fp32.
// d_out layout: h_new (256*512) | c_new (256*512) | hebb_new (256*512*512)

#define HSZ 512
#define G4  2048   // 4*HS

__device__ __forceinline__ float sigm(float x) { return 1.0f / (1.0f + __expf(-x)); }
__device__ __forceinline__ float clip2(float v) { return fminf(fmaxf(v, -2.0f), 2.0f); }

// ---------------------------------------------------------------------------
// Kernel 1: raw gates = [x|h] @ [W;U] + bias  -> ws (256 x 2048), fp32 SIMT GEMM
// 64x64 block tile, 256 threads, 4x4 micro-tile, K-step 16.
// ---------------------------------------------------------------------------
__global__ __launch_bounds__(256, 4)
void gates_gemm(const float* __restrict__ x, const float* __restrict__ h,
                const float* __restrict__ W, const float* __restrict__ U,
                const float* __restrict__ bias, float* __restrict__ gates)
{
    __shared__ float As[16][68];   // [k][row], padded for bank spread + 16B align
    __shared__ float Bs[16][64];   // [k][col]

    const int t     = threadIdx.x;
    const int brow0 = blockIdx.y * 64;   // batch rows
    const int bcol0 = blockIdx.x * 64;   // gate cols

    const int tr = t & 15;          // micro-tile row group
    const int tc = t >> 4;          // micro-tile col group
    const int arow = t >> 2, ak4 = (t & 3) * 4;
    const int brow = t >> 4, bc4 = (t & 15) * 4;

    float acc[4][4] = {};

    for (int ks = 0; ks < 64; ++ks) {
        const float* srcA;
        const float* srcB;
        int k0;
        if (ks < 32) { srcA = x; srcB = W; k0 = ks * 16; }
        else         { srcA = h; srcB = U; k0 = ks * 16 - 512; }

        float4 av = *(const float4*)&srcA[(size_t)(brow0 + arow) * 512 + k0 + ak4];
        float4 bv = *(const float4*)&srcB[(size_t)(k0 + brow) * 2048 + bcol0 + bc4];

        __syncthreads();   // previous iteration done reading LDS
        As[ak4 + 0][arow] = av.x;
        As[ak4 + 1][arow] = av.y;
        As[ak4 + 2][arow] = av.z;
        As[ak4 + 3][arow] = av.w;
        *(float4*)&Bs[brow][bc4] = bv;
        __syncthreads();

        #pragma unroll
        for (int kk = 0; kk < 16; ++kk) {
            float4 a = *(float4*)&As[kk][tr * 4];
            float4 b = *(float4*)&Bs[kk][tc * 4];
            acc[0][0] += a.x * b.x; acc[0][1] += a.x * b.y; acc[0][2] += a.x * b.z; acc[0][3] += a.x * b.w;
            acc[1][0] += a.y * b.x; acc[1][1] += a.y * b.y; acc[1][2] += a.y * b.z; acc[1][3] += a.y * b.w;
            acc[2][0] += a.z * b.x; acc[2][1] += a.z * b.y; acc[2][2] += a.z * b.z; acc[2][3] += a.z * b.w;
            acc[3][0] += a.w * b.x; acc[3][1] += a.w * b.y; acc[3][2] += a.w * b.z; acc[3][3] += a.w * b.w;
        }
    }

    float4 bb = *(const float4*)&bias[bcol0 + tc * 4];
    #pragma unroll
    for (int rr = 0; rr < 4; ++rr) {
        const int row = brow0 + tr * 4 + rr;
        float4 o;
        o.x = acc[rr][0] + bb.x;
        o.y = acc[rr][1] + bb.y;
        o.z = acc[rr][2] + bb.z;
        o.w = acc[rr][3] + bb.w;
        *(float4*)&gates[(size_t)row * 2048 + bcol0 + tc * 4] = o;
    }
}

// ---------------------------------------------------------------------------
// Kernel 2: fused hebb reduce + update + LSTM epilogue.
// Grid: 256 b * 16 j-tiles. Block: 256 threads.
// Each block owns hebb[b, :, j0:j0+32] (512x32 fp32 = 64KB) in registers:
// thread (ti in [0,32), tj4 in [0,8)) holds rows i = ti*16..+16, cols j0+tj4*4..+4
// as 16 float4 (64 VGPRs).
// ---------------------------------------------------------------------------
__global__ __launch_bounds__(256, 4)
void hebb_fused(const float* __restrict__ h_t, const float* __restrict__ c_t,
                const float* __restrict__ hebb, const float* __restrict__ alpha,
                const float* __restrict__ nm_w, const float* __restrict__ nm_b,
                const float* __restrict__ mt_w, const float* __restrict__ mt_b,
                const float* __restrict__ gates, float* __restrict__ out)
{
    const int b   = blockIdx.x >> 4;
    const int jt  = blockIdx.x & 15;
    const int j0  = jt * 32;
    const int t   = threadIdx.x;
    const int tj4 = t & 7;     // float4 column group within tile
    const int ti  = t >> 3;    // row group (16 rows each)

    __shared__ float hsh[512];
    __shared__ float red[32][32];
    __shared__ float upd[32];
    __shared__ float redm[256];
    __shared__ float msh;

    // --- hebb slab load (issue early; 16 dwordx4 per thread, coalesced) ---
    const float4* hb    = (const float4*)(hebb + (size_t)b * 262144);
    const int     cbase = (j0 >> 2) + tj4;      // float4 column index, row pitch 128
    float4 r[16];
    #pragma unroll
    for (int k = 0; k < 16; ++k)
        r[k] = hb[(size_t)(ti * 16 + k) * 128 + cbase];

    // --- stage h row ---
    hsh[t]       = h_t[(size_t)b * 512 + t];
    hsh[t + 256] = h_t[(size_t)b * 512 + t + 256];
    __syncthreads();

    // --- m_t = tanh(dot(h, nm_w) + nm_b): block reduction ---
    redm[t] = hsh[t] * nm_w[t] + hsh[t + 256] * nm_w[t + 256];
    __syncthreads();
    if (t < 128) redm[t] += redm[t + 128];
    __syncthreads();
    if (t < 64)  redm[t] += redm[t + 64];
    __syncthreads();
    if (t < 64) {
        float v = redm[t];
        #pragma unroll
        for (int off = 32; off > 0; off >>= 1) v += __shfl_down(v, off);
        if (t == 0) msh = tanhf(v + nm_b[0]);
    }

    // --- column partial sums: ps[c] = sum_k h[i]*hebb[i,j] over this thread's rows ---
    float4 ps = {0.f, 0.f, 0.f, 0.f};
    #pragma unroll
    for (int k = 0; k < 16; ++k) {
        const float hv = hsh[ti * 16 + k];
        ps.x += hv * r[k].x;
        ps.y += hv * r[k].y;
        ps.z += hv * r[k].z;
        ps.w += hv * r[k].w;
    }
    *(float4*)&red[ti][tj4 * 4] = ps;
    __syncthreads();   // also makes msh visible

    // --- per-column finalize: g_t, update factor, and LSTM epilogue ---
    if (t < 32) {
        float s = 0.f;
        #pragma unroll
        for (int q = 0; q < 32; ++q) s += red[q][t];
        const int j = j0 + t;
        const size_t gbase = (size_t)b * 2048;
        const float g  = tanhf(gates[gbase + 1024 + j] + alpha[j] * s);
        const float mm = msh * mt_w[j] + mt_b[j];
        upd[t] = mm * g;
        const float it_ = sigm(gates[gbase + j]);
        const float ft  = sigm(gates[gbase + 512 + j]);
        const float ot  = sigm(gates[gbase + 1536 + j]);
        const float cn  = ft * c_t[(size_t)b * 512 + j] + it_ * g;
        out[(size_t)b * 512 + j]          = ot * tanhf(cn);   // h_new
        out[131072 + (size_t)b * 512 + j] = cn;               // c_new
    }
    __syncthreads();

    // --- hebb update + clip + store ---
    const float4 u = *(float4*)&upd[tj4 * 4];
    float4* ho = (float4*)(out + 262144 + (size_t)b * 262144);
    #pragma unroll
    for (int k = 0; k < 16; ++k) {
        const float hv = hsh[ti * 16 + k];
        float4 w;
        w.x = clip2(r[k].x + u.x * hv);
        w.y = clip2(r[k].y + u.y * hv);
        w.z = clip2(r[k].z + u.z * hv);
        w.w = clip2(r[k].w + u.w * hv);
        ho[(size_t)(ti * 16 + k) * 128 + cbase] = w;
    }
}

extern "C" void kernel_launch(void* const* d_in, const int* in_sizes, int n_in,
                              void* d_out, int out_size, void* d_ws, size_t ws_size,
                              hipStream_t stream)
{
    const float* x_t   = (const float*)d_in[0];
    const float* h_t   = (const float*)d_in[1];
    const float* c_t   = (const float*)d_in[2];
    const float* hebb  = (const float*)d_in[3];
    const float* W     = (const float*)d_in[4];
    const float* U     = (const float*)d_in[5];
    const float* bias  = (const float*)d_in[6];
    const float* alpha = (const float*)d_in[7];
    const float* nm_w  = (const float*)d_in[8];
    const float* nm_b  = (const float*)d_in[9];
    const float* mt_w  = (const float*)d_in[10];
    const float* mt_b  = (const float*)d_in[11];
    float* out   = (float*)d_out;
    float* gates = (float*)d_ws;   // 256*2048 fp32 = 2 MB raw gates

    dim3 g1(32, 4);   // 2048/64 cols x 256/64 rows
    gates_gemm<<<g1, 256, 0, stream>>>(x_t, h_t, W, U, bias, gates);
    hebb_fused<<<4096, 256, 0, stream>>>(h_t, c_t, hebb, alpha, nm_w, nm_b,
                                         mt_w, mt_b, gates, out);
}

// Round 2
// 505.779 us; speedup vs baseline: 1.0763x; 1.0763x over previous
//
#include <hip/hip_runtime.h>
#include <math.h>

// NM-LSTM step, B=256, IN=HS=512, NM=1, fp32.
// d_out layout: h_new (256*512) | c_new (256*512) | hebb_new (256*512*512)

__device__ __forceinline__ float sigm(float x) { return 1.0f / (1.0f + __expf(-x)); }
__device__ __forceinline__ float clip2(float v) { return fminf(fmaxf(v, -2.0f), 2.0f); }

// ---------------------------------------------------------------------------
// Kernel 1: raw gates = [x|h] @ [W;U] + bias -> ws (256 x 2048), fp32.
// Row-in-register / B-broadcast design: 64x32 tile, 256 threads.
// thread t: output row = t&63, col group cg = t>>6 (8 cols each).
// Per k: A via ds_read_b32 (lanes = consecutive rows, 2-way free),
//        B via wave-uniform LDS read (broadcast). 8 FMA per 4B+broadcast.
// ---------------------------------------------------------------------------
__global__ __launch_bounds__(256, 4)
void gates_gemm(const float* __restrict__ x, const float* __restrict__ h,
                const float* __restrict__ W, const float* __restrict__ U,
                const float* __restrict__ bias, float* __restrict__ gates)
{
    __shared__ float As[64][64];   // [k][row]
    __shared__ float Bs[64][40];   // [k][col], padded pitch 40 (160B, 16B-aligned)

    const int t     = threadIdx.x;
    const int bcol0 = blockIdx.x * 32;
    const int brow0 = blockIdx.y * 64;
    const int row   = t & 63;
    const int cg    = t >> 6;      // 0..3, 8 cols each

    float acc[8] = {};

    for (int ks = 0; ks < 16; ++ks) {
        const float* srcA;
        const float* srcB;
        int ka;
        if (ks < 8) { srcA = x; srcB = W; ka = ks * 64; }
        else        { srcA = h; srcB = U; ka = ks * 64 - 512; }

        // A: thread loads 16 floats of its row segment
        float4 av[4];
        #pragma unroll
        for (int m = 0; m < 4; ++m)
            av[m] = *(const float4*)&srcA[(size_t)(brow0 + row) * 512 + ka + cg * 16 + m * 4];
        // B: 64 rows x 8 float4; 2 per thread
        const int kr0 = t >> 3;        // 0..31
        const int c4  = t & 7;         // 0..7
        float4 bv0 = *(const float4*)&srcB[(size_t)(ka + kr0)      * 2048 + bcol0 + c4 * 4];
        float4 bv1 = *(const float4*)&srcB[(size_t)(ka + kr0 + 32) * 2048 + bcol0 + c4 * 4];

        __syncthreads();   // previous iteration done reading LDS
        #pragma unroll
        for (int m = 0; m < 4; ++m) {
            As[cg * 16 + m * 4 + 0][row] = av[m].x;
            As[cg * 16 + m * 4 + 1][row] = av[m].y;
            As[cg * 16 + m * 4 + 2][row] = av[m].z;
            As[cg * 16 + m * 4 + 3][row] = av[m].w;
        }
        *(float4*)&Bs[kr0][c4 * 4]      = bv0;
        *(float4*)&Bs[kr0 + 32][c4 * 4] = bv1;
        __syncthreads();

        #pragma unroll
        for (int k = 0; k < 64; ++k) {
            const float a = As[k][row];
            const float4 b0 = *(const float4*)&Bs[k][cg * 8];
            const float4 b1 = *(const float4*)&Bs[k][cg * 8 + 4];
            acc[0] += a * b0.x; acc[1] += a * b0.y; acc[2] += a * b0.z; acc[3] += a * b0.w;
            acc[4] += a * b1.x; acc[5] += a * b1.y; acc[6] += a * b1.z; acc[7] += a * b1.w;
        }
    }

    const int colb = bcol0 + cg * 8;
    float4 o0, o1;
    o0.x = acc[0] + bias[colb + 0]; o0.y = acc[1] + bias[colb + 1];
    o0.z = acc[2] + bias[colb + 2]; o0.w = acc[3] + bias[colb + 3];
    o1.x = acc[4] + bias[colb + 4]; o1.y = acc[5] + bias[colb + 5];
    o1.z = acc[6] + bias[colb + 6]; o1.w = acc[7] + bias[colb + 7];
    float* gp = &gates[(size_t)(brow0 + row) * 2048 + colb];
    *(float4*)gp       = o0;
    *(float4*)(gp + 4) = o1;
}

// ---------------------------------------------------------------------------
// Kernel 2: fused hebb reduce + update + LSTM epilogue.
// Grid: 256 b * 8 j-tiles (64 cols). Block: 512 threads.
// Each block owns hebb[b, :, j0:j0+64] (512x64 fp32 = 128KB) in registers:
// thread (ti = t>>4 in [0,32), tj4 = t&15) holds rows ti*16..+16,
// float4-cols j0/4+tj4, as 16 float4 (64 VGPRs).
// Wave load contiguity: 16 lanes x 16B = 256B chunks (was 128B at 32-col tile).
// ---------------------------------------------------------------------------
__global__ __launch_bounds__(512, 4)
void hebb_fused(const float* __restrict__ h_t, const float* __restrict__ c_t,
                const float* __restrict__ hebb, const float* __restrict__ alpha,
                const float* __restrict__ nm_w, const float* __restrict__ nm_b,
                const float* __restrict__ mt_w, const float* __restrict__ mt_b,
                const float* __restrict__ gates, float* __restrict__ out)
{
    const int b   = blockIdx.x >> 3;
    const int jt  = blockIdx.x & 7;
    const int j0  = jt * 64;
    const int t   = threadIdx.x;
    const int tj4 = t & 15;    // float4 column group within tile
    const int ti  = t >> 4;    // row group (16 rows each), 0..31

    __shared__ float hsh[512];
    __shared__ float red[32][64];
    __shared__ float upd[64];
    __shared__ float redm[512];
    __shared__ float msh;

    // --- hebb slab load (issue early; 16 dwordx4 per thread) ---
    const float4* hb    = (const float4*)(hebb + (size_t)b * 262144);
    const int     cbase = jt * 16 + tj4;          // float4 column index, row pitch 128
    float4 r[16];
    #pragma unroll
    for (int k = 0; k < 16; ++k)
        r[k] = hb[(size_t)(ti * 16 + k) * 128 + cbase];

    // --- stage h row + m_t partials ---
    const float hv0 = h_t[(size_t)b * 512 + t];
    hsh[t]  = hv0;
    redm[t] = hv0 * nm_w[t];
    __syncthreads();

    // --- m_t reduction on wave 0 (overlaps other waves' ps work) ---
    if (t < 64) {
        float v = 0.f;
        #pragma unroll
        for (int q = 0; q < 8; ++q) v += redm[t + q * 64];
        #pragma unroll
        for (int off = 32; off > 0; off >>= 1) v += __shfl_down(v, off);
        if (t == 0) msh = tanhf(v + nm_b[0]);
    }

    // --- column partial sums over this thread's 16 rows ---
    float4 ps = {0.f, 0.f, 0.f, 0.f};
    #pragma unroll
    for (int k = 0; k < 16; ++k) {
        const float hv = hsh[ti * 16 + k];
        ps.x += hv * r[k].x;
        ps.y += hv * r[k].y;
        ps.z += hv * r[k].z;
        ps.w += hv * r[k].w;
    }
    *(float4*)&red[ti][tj4 * 4] = ps;
    __syncthreads();   // also makes msh visible

    // --- per-column finalize: g_t, update factor, LSTM epilogue ---
    if (t < 64) {
        float s = 0.f;
        #pragma unroll
        for (int q = 0; q < 32; ++q) s += red[q][t];
        const int j = j0 + t;
        const size_t gbase = (size_t)b * 2048;
        const float g  = tanhf(gates[gbase + 1024 + j] + alpha[j] * s);
        const float mm = msh * mt_w[j] + mt_b[j];
        upd[t] = mm * g;
        const float it_ = sigm(gates[gbase + j]);
        const float ft  = sigm(gates[gbase + 512 + j]);
        const float ot  = sigm(gates[gbase + 1536 + j]);
        const float cn  = ft * c_t[(size_t)b * 512 + j] + it_ * g;
        out[(size_t)b * 512 + j]          = ot * tanhf(cn);   // h_new
        out[131072 + (size_t)b * 512 + j] = cn;               // c_new
    }
    __syncthreads();

    // --- hebb update + clip + store ---
    const float4 u = *(const float4*)&upd[tj4 * 4];
    float4* ho = (float4*)(out + 262144 + (size_t)b * 262144);
    #pragma unroll
    for (int k = 0; k < 16; ++k) {
        const float hv = hsh[ti * 16 + k];
        float4 w;
        w.x = clip2(r[k].x + u.x * hv);
        w.y = clip2(r[k].y + u.y * hv);
        w.z = clip2(r[k].z + u.z * hv);
        w.w = clip2(r[k].w + u.w * hv);
        ho[(size_t)(ti * 16 + k) * 128 + cbase] = w;
    }
}

extern "C" void kernel_launch(void* const* d_in, const int* in_sizes, int n_in,
                              void* d_out, int out_size, void* d_ws, size_t ws_size,
                              hipStream_t stream)
{
    const float* x_t   = (const float*)d_in[0];
    const float* h_t   = (const float*)d_in[1];
    const float* c_t   = (const float*)d_in[2];
    const float* hebb  = (const float*)d_in[3];
    const float* W     = (const float*)d_in[4];
    const float* U     = (const float*)d_in[5];
    const float* bias  = (const float*)d_in[6];
    const float* alpha = (const float*)d_in[7];
    const float* nm_w  = (const float*)d_in[8];
    const float* nm_b  = (const float*)d_in[9];
    const float* mt_w  = (const float*)d_in[10];
    const float* mt_b  = (const float*)d_in[11];
    float* out   = (float*)d_out;
    float* gates = (float*)d_ws;   // 256*2048 fp32 = 2 MB raw gates

    dim3 g1(64, 4);   // 2048/32 col-tiles x 256/64 row-tiles = 256 blocks
    gates_gemm<<<g1, 256, 0, stream>>>(x_t, h_t, W, U, bias, gates);
    hebb_fused<<<2048, 512, 0, stream>>>(h_t, c_t, hebb, alpha, nm_w, nm_b,
                                         mt_w, mt_b, gates, out);
}